// Round 4
// baseline (1997.943 us; speedup 1.0000x reference)
//
#include <hip/hip_runtime.h>
#include <hip/hip_bf16.h>
#include <cstddef>
#include <cstdint>
#include <math.h>

// Problem constants (Qwen2MoE attention, B=2, S=2048)
#define H_    2048
#define NH_   16
#define NKV_  4
#define HD_   128
#define S_    2048
#define B_    2
#define M_    (B_ * S_)        // 4096 rows
#define QKV_N 3072             // (NH + 2*NKV) * HD

typedef unsigned short u16;
typedef __attribute__((ext_vector_type(8))) short s16x8;   // 8 bf16 (4 VGPRs)
typedef __attribute__((ext_vector_type(4))) float f32x4;   // MFMA C/D

__device__ inline u16 f2bf(float x) {
  __hip_bfloat16 h = __float2bfloat16(x);
  return *reinterpret_cast<u16*>(&h);
}
__device__ inline float bf2f(u16 u) {
  __hip_bfloat16 h;
  *reinterpret_cast<u16*>(&h) = u;
  return __bfloat162float(h);
}

__device__ inline f32x4 mfma_bf16(s16x8 a, s16x8 b, f32x4 c) {
  return __builtin_amdgcn_mfma_f32_16x16x32_bf16(a, b, c, 0, 0, 0);
}

#define GLOAD(g, s)                                                  \
  __builtin_amdgcn_global_load_lds(                                  \
      (const __attribute__((address_space(1))) void*)(g),            \
      (__attribute__((address_space(3))) void*)(s), 16, 0, 0)

// ---------------------------------------------------------------------------
// split fp32 -> (hi, lo) bf16, elementwise (for A matrices, [M][K] layout)
// ---------------------------------------------------------------------------
__global__ __launch_bounds__(256) void split_f32(
    const float* __restrict__ in, u16* __restrict__ hi, u16* __restrict__ lo,
    int n4) {
  int i = blockIdx.x * 256 + threadIdx.x;
  if (i >= n4) return;
  float4 v = reinterpret_cast<const float4*>(in)[i];
  float x[4] = {v.x, v.y, v.z, v.w};
  u16 hv[4], lv[4];
#pragma unroll
  for (int j = 0; j < 4; ++j) {
    hv[j] = f2bf(x[j]);
    lv[j] = f2bf(x[j] - bf2f(hv[j]));
  }
  reinterpret_cast<ushort4*>(hi)[i] = make_ushort4(hv[0], hv[1], hv[2], hv[3]);
  reinterpret_cast<ushort4*>(lo)[i] = make_ushort4(lv[0], lv[1], lv[2], lv[3]);
}

// ---------------------------------------------------------------------------
// split + transpose: W[K][N] fp32 -> Wt_hi/lo[N][K] bf16 (64x64 LDS tile)
// ---------------------------------------------------------------------------
__global__ __launch_bounds__(256) void split_transpose(
    const float* __restrict__ W, u16* __restrict__ thi, u16* __restrict__ tlo,
    int K, int N) {
  __shared__ float tile[64][65];
  const int t  = threadIdx.x;
  const int rr = t >> 4;          // 0..15
  const int c4 = (t & 15) * 4;    // 0..60
  const int k0 = blockIdx.x * 64;
  const int n0 = blockIdx.y * 64;
#pragma unroll
  for (int s = 0; s < 4; ++s) {
    int kk = rr + 16 * s;
    float4 v = *reinterpret_cast<const float4*>(&W[(size_t)(k0 + kk) * N + n0 + c4]);
    tile[kk][c4 + 0] = v.x; tile[kk][c4 + 1] = v.y;
    tile[kk][c4 + 2] = v.z; tile[kk][c4 + 3] = v.w;
  }
  __syncthreads();
#pragma unroll
  for (int s = 0; s < 4; ++s) {
    int nn = rr + 16 * s;
    u16 hv[4], lv[4];
#pragma unroll
    for (int j = 0; j < 4; ++j) {
      float x = tile[c4 + j][nn];
      hv[j] = f2bf(x);
      lv[j] = f2bf(x - bf2f(hv[j]));
    }
    size_t o = (size_t)(n0 + nn) * K + k0 + c4;
    *reinterpret_cast<ushort4*>(&thi[o]) = make_ushort4(hv[0], hv[1], hv[2], hv[3]);
    *reinterpret_cast<ushort4*>(&tlo[o]) = make_ushort4(lv[0], lv[1], lv[2], lv[3]);
  }
}

// ---------------------------------------------------------------------------
// bf16x3 split MFMA GEMM: C[M][N] = A[M][K] @ Bt[N][K]^T (+bias), fp32 out.
// 128x128 tile, BK=32, 4 waves, 16x16x32 bf16 MFMA, 3 products (hh, lh, hl).
// global_load_lds staging with both-sides XOR slot swizzle (rule #21):
//   stage: lane l fetches global slot (l&3)^((l>>3)&3) -> linear LDS dest
//   read : lane l reads LDS slot  (l>>4)^(((l&15)>>1)&3)
// Resolves to global slot l>>4 per fragment row = the MFMA layout; read lands
// 2-way bank-aliased per 16-lane phase (free, m136) instead of 8-way.
// ---------------------------------------------------------------------------
__global__ __launch_bounds__(256, 2) void gemm_bf16x3(
    const u16* __restrict__ Ahi, const u16* __restrict__ Alo,
    const u16* __restrict__ Bthi, const u16* __restrict__ Btlo,
    const float* __restrict__ bias, float* __restrict__ C,
    int M, int N, int K) {
  __shared__ u16 lds[4][128][32];  // 0:Ahi 1:Alo 2:Bhi 3:Blo — 32 KiB

  const int t  = threadIdx.x;
  const int l  = t & 63;
  const int w  = t >> 6;
  const int wr = w >> 1, wc = w & 1;      // wave -> 64x64 quadrant
  const int row0 = blockIdx.x * 128;
  const int col0 = blockIdx.y * 128;

  f32x4 acc[4][4] = {};

  const int srow  = l >> 2;                        // stage: row within 16-seg
  const int gslot = (l & 3) ^ ((l >> 3) & 3);      // stage: swizzled src slot
  const int fr    = l & 15;                        // frag row
  const int rslot = (l >> 4) ^ ((fr >> 1) & 3);    // read: swizzled slot

  for (int k0 = 0; k0 < K; k0 += 32) {
#pragma unroll
    for (int it = 0; it < 2; ++it) {
      const int r0 = (w + 4 * it) * 16;
      const size_t ga = (size_t)(row0 + r0 + srow) * K + k0 + gslot * 8;
      GLOAD(Ahi + ga, &lds[0][r0][0]);
      GLOAD(Alo + ga, &lds[1][r0][0]);
      const size_t gb = (size_t)(col0 + r0 + srow) * K + k0 + gslot * 8;
      GLOAD(Bthi + gb, &lds[2][r0][0]);
      GLOAD(Btlo + gb, &lds[3][r0][0]);
    }
    __syncthreads();  // compiler drains vmcnt(0) before barrier

    s16x8 ah[4], al[4];
#pragma unroll
    for (int f = 0; f < 4; ++f) {
      const int ar = wr * 64 + f * 16 + fr;
      ah[f] = *reinterpret_cast<const s16x8*>(&lds[0][ar][rslot * 8]);
      al[f] = *reinterpret_cast<const s16x8*>(&lds[1][ar][rslot * 8]);
    }
#pragma unroll
    for (int j = 0; j < 4; ++j) {
      const int br = wc * 64 + j * 16 + fr;
      const s16x8 bh = *reinterpret_cast<const s16x8*>(&lds[2][br][rslot * 8]);
      const s16x8 bl = *reinterpret_cast<const s16x8*>(&lds[3][br][rslot * 8]);
#pragma unroll
      for (int i = 0; i < 4; ++i) {
        acc[i][j] = mfma_bf16(ah[i], bh, acc[i][j]);
        acc[i][j] = mfma_bf16(al[i], bh, acc[i][j]);
        acc[i][j] = mfma_bf16(ah[i], bl, acc[i][j]);
      }
    }
    __syncthreads();
  }

  // epilogue: C/D layout col=lane&15, row=(lane>>4)*4+reg (m89-verified)
  const int rb = (l >> 4) * 4;
  const int cn = l & 15;
  float bv[4];
#pragma unroll
  for (int j = 0; j < 4; ++j)
    bv[j] = bias ? bias[col0 + wc * 64 + j * 16 + cn] : 0.f;
#pragma unroll
  for (int i = 0; i < 4; ++i)
#pragma unroll
    for (int j = 0; j < 4; ++j) {
      const int col = col0 + wc * 64 + j * 16 + cn;
#pragma unroll
      for (int r = 0; r < 4; ++r) {
        const int row = row0 + wr * 64 + i * 16 + rb + r;
        C[(size_t)row * N + col] = acc[i][j][r] + bv[j];
      }
    }
}

// ---------------------------------------------------------------------------
// fp32 fallback GEMM (small-ws fallback path; r1-proven)
// ---------------------------------------------------------------------------
#define BT 128
#define BK 16
__global__ __launch_bounds__(256, 2) void sgemm_bias(
    const float* __restrict__ A, const float* __restrict__ W,
    const float* __restrict__ bias, float* __restrict__ C,
    int M, int N, int K) {
  __shared__ float As[BK][BT + 4];
  __shared__ float Bs[BK][BT + 4];
  const int t  = threadIdx.x;
  const int tx = t & 15;
  const int ty = t >> 4;
  const int row0 = blockIdx.x * BT;
  const int col0 = blockIdx.y * BT;
  float acc[8][8];
#pragma unroll
  for (int i = 0; i < 8; ++i)
#pragma unroll
    for (int j = 0; j < 8; ++j) acc[i][j] = 0.f;
  for (int k0 = 0; k0 < K; k0 += BK) {
#pragma unroll
    for (int it = 0; it < 2; ++it) {
      int idx = t + 256 * it;
      int r   = idx >> 2;
      int kq  = idx & 3;
      const float4 a4 = *reinterpret_cast<const float4*>(
          A + (size_t)(row0 + r) * K + k0 + kq * 4);
      As[kq * 4 + 0][r] = a4.x; As[kq * 4 + 1][r] = a4.y;
      As[kq * 4 + 2][r] = a4.z; As[kq * 4 + 3][r] = a4.w;
    }
#pragma unroll
    for (int it = 0; it < 2; ++it) {
      int idx = t + 256 * it;
      int kk  = idx >> 5;
      int c4  = idx & 31;
      *reinterpret_cast<float4*>(&Bs[kk][c4 * 4]) =
          *reinterpret_cast<const float4*>(W + (size_t)(k0 + kk) * N + col0 + c4 * 4);
    }
    __syncthreads();
#pragma unroll
    for (int k = 0; k < BK; ++k) {
      float a[8], b[8];
      *reinterpret_cast<float4*>(&a[0]) = *reinterpret_cast<const float4*>(&As[k][ty * 8]);
      *reinterpret_cast<float4*>(&a[4]) = *reinterpret_cast<const float4*>(&As[k][ty * 8 + 4]);
      *reinterpret_cast<float4*>(&b[0]) = *reinterpret_cast<const float4*>(&Bs[k][tx * 8]);
      *reinterpret_cast<float4*>(&b[4]) = *reinterpret_cast<const float4*>(&Bs[k][tx * 8 + 4]);
#pragma unroll
      for (int i = 0; i < 8; ++i)
#pragma unroll
        for (int j = 0; j < 8; ++j) acc[i][j] = fmaf(a[i], b[j], acc[i][j]);
    }
    __syncthreads();
  }
  float bv[8];
#pragma unroll
  for (int j = 0; j < 8; ++j) bv[j] = 0.f;
  if (bias != nullptr) {
    *reinterpret_cast<float4*>(&bv[0]) = *reinterpret_cast<const float4*>(&bias[col0 + tx * 8]);
    *reinterpret_cast<float4*>(&bv[4]) = *reinterpret_cast<const float4*>(&bias[col0 + tx * 8 + 4]);
  }
#pragma unroll
  for (int i = 0; i < 8; ++i) {
    float* crow = C + (size_t)(row0 + ty * 8 + i) * N + col0 + tx * 8;
    float4 w0, w1;
    w0.x = acc[i][0] + bv[0]; w0.y = acc[i][1] + bv[1];
    w0.z = acc[i][2] + bv[2]; w0.w = acc[i][3] + bv[3];
    w1.x = acc[i][4] + bv[4]; w1.y = acc[i][5] + bv[5];
    w1.z = acc[i][6] + bv[6]; w1.w = acc[i][7] + bv[7];
    *reinterpret_cast<float4*>(crow)     = w0;
    *reinterpret_cast<float4*>(crow + 4) = w1;
  }
}

// ---------------------------------------------------------------------------
// RoPE (in-place on q and k sections of qkv)
// ---------------------------------------------------------------------------
__global__ __launch_bounds__(256) void rope_kernel(
    float* __restrict__ qkv, const int* __restrict__ positions) {
  int idx = blockIdx.x * 256 + threadIdx.x;
  const int total = M_ * (NH_ + NKV_) * (HD_ / 2);
  if (idx >= total) return;
  int j    = idx & 63;
  int head = (idx >> 6) % (NH_ + NKV_);
  int m    = idx / (64 * (NH_ + NKV_));
  float pos = (float)positions[m];
  float inv_freq = powf(1.0e6f, -(float)j * (1.0f / 64.0f));
  float ang = pos * inv_freq;
  float sn, cs;
  sincosf(ang, &sn, &cs);
  float* ptr = qkv + (size_t)m * QKV_N + head * HD_ + j;
  float x1 = ptr[0], x2 = ptr[64];
  ptr[0]  = x1 * cs - x2 * sn;
  ptr[64] = x2 * cs + x1 * sn;
}

// ---------------------------------------------------------------------------
// fp32 flash attention (causal, GQA group=4). Epilogue emits either split
// hi/lo bf16 (feeds gemm_bf16x3 directly) or fp32 (fallback path).
// ---------------------------------------------------------------------------
__global__ __launch_bounds__(256) void flash_attn(
    const float* __restrict__ qkv, float* __restrict__ attn_f32,
    u16* __restrict__ attn_hi, u16* __restrict__ attn_lo, int split) {
  __shared__ float Qt[HD_][64];
  __shared__ float Kt[HD_][64];
  float(*Vs)[HD_] = reinterpret_cast<float(*)[HD_]>(&Kt[0][0]);

  const int t    = threadIdx.x;
  const int lane = t & 63;
  const int tr   = t >> 4;
  const int tc   = t & 15;
  const int bid  = blockIdx.x;
  const int qt   = bid & 31;
  const int bh   = bid >> 5;
  const int h    = bh & 15;
  const int b    = bh >> 4;
  const int kvh  = h >> 2;

  const float* Qg = qkv + ((size_t)(b * S_) + qt * 64) * QKV_N + h * HD_;
  const float* Kg = qkv + (size_t)(b * S_) * QKV_N + NH_ * HD_ + kvh * HD_;
  const float* Vg = Kg + NKV_ * HD_;

#pragma unroll
  for (int part = 0; part < 4; ++part)
#pragma unroll
    for (int half = 0; half < 2; ++half) {
      int c4 = (t & 7) + 8 * part;
      int r  = (t >> 3) + 32 * half;
      float4 v = *reinterpret_cast<const float4*>(Qg + (size_t)r * QKV_N + c4 * 4);
      Qt[c4 * 4 + 0][r] = v.x; Qt[c4 * 4 + 1][r] = v.y;
      Qt[c4 * 4 + 2][r] = v.z; Qt[c4 * 4 + 3][r] = v.w;
    }

  float m_i[4], l_i[4], o[4][8];
#pragma unroll
  for (int i = 0; i < 4; ++i) {
    m_i[i] = -INFINITY;
    l_i[i] = 0.f;
#pragma unroll
    for (int j = 0; j < 8; ++j) o[i][j] = 0.f;
  }

  const int nkt = qt + 1;

  float4 kreg[8];
#pragma unroll
  for (int part = 0; part < 4; ++part)
#pragma unroll
    for (int half = 0; half < 2; ++half) {
      int c4 = (t & 7) + 8 * part;
      int r  = (t >> 3) + 32 * half;
      kreg[part * 2 + half] =
          *reinterpret_cast<const float4*>(Kg + (size_t)r * QKV_N + c4 * 4);
    }
  __syncthreads();
#pragma unroll
  for (int part = 0; part < 4; ++part)
#pragma unroll
    for (int half = 0; half < 2; ++half) {
      int c4 = (t & 7) + 8 * part;
      int r  = (t >> 3) + 32 * half;
      float4 v = kreg[part * 2 + half];
      Kt[c4 * 4 + 0][r] = v.x; Kt[c4 * 4 + 1][r] = v.y;
      Kt[c4 * 4 + 2][r] = v.z; Kt[c4 * 4 + 3][r] = v.w;
    }
  __syncthreads();

  const float scale = 0.08838834764831845f;

  for (int kt = 0; kt < nkt; ++kt) {
    const bool more = (kt + 1 < nkt);

    float4 vreg[8];
#pragma unroll
    for (int it = 0; it < 8; ++it) {
      int c4 = t & 31;
      int k  = (t >> 5) + 8 * it;
      vreg[it] = *reinterpret_cast<const float4*>(
          Vg + (size_t)(kt * 64 + k) * QKV_N + c4 * 4);
    }

    float p[4][4];
#pragma unroll
    for (int i = 0; i < 4; ++i)
#pragma unroll
      for (int j = 0; j < 4; ++j) p[i][j] = 0.f;

#pragma unroll 8
    for (int d = 0; d < HD_; ++d) {
      float av[4], bvv[4];
      *reinterpret_cast<float4*>(av)  = *reinterpret_cast<const float4*>(&Qt[d][tr * 4]);
      *reinterpret_cast<float4*>(bvv) = *reinterpret_cast<const float4*>(&Kt[d][tc * 4]);
#pragma unroll
      for (int i = 0; i < 4; ++i)
#pragma unroll
        for (int j = 0; j < 4; ++j) p[i][j] = fmaf(av[i], bvv[j], p[i][j]);
    }

#pragma unroll
    for (int i = 0; i < 4; ++i)
#pragma unroll
      for (int j = 0; j < 4; ++j) {
        float sv = p[i][j] * scale;
        if (kt == qt && (tc * 4 + j > tr * 4 + i)) sv = -3.402823466e38f;
        p[i][j] = sv;
      }

    float rm[4], rs[4], alpha[4];
#pragma unroll
    for (int i = 0; i < 4; ++i)
      rm[i] = fmaxf(fmaxf(p[i][0], p[i][1]), fmaxf(p[i][2], p[i][3]));
#pragma unroll
    for (int off = 1; off < 16; off <<= 1)
#pragma unroll
      for (int i = 0; i < 4; ++i)
        rm[i] = fmaxf(rm[i], __shfl_xor(rm[i], off, 64));
#pragma unroll
    for (int i = 0; i < 4; ++i) {
      float mnew = fmaxf(m_i[i], rm[i]);
      alpha[i] = expf(m_i[i] - mnew);
      m_i[i] = mnew;
      float s = 0.f;
#pragma unroll
      for (int j = 0; j < 4; ++j) {
        p[i][j] = expf(p[i][j] - mnew);
        s += p[i][j];
      }
      rs[i] = s;
    }
#pragma unroll
    for (int off = 1; off < 16; off <<= 1)
#pragma unroll
      for (int i = 0; i < 4; ++i) rs[i] += __shfl_xor(rs[i], off, 64);
#pragma unroll
    for (int i = 0; i < 4; ++i) {
      l_i[i] = l_i[i] * alpha[i] + rs[i];
#pragma unroll
      for (int j = 0; j < 8; ++j) o[i][j] *= alpha[i];
    }

    __syncthreads();
#pragma unroll
    for (int it = 0; it < 8; ++it) {
      int c4 = t & 31;
      int k  = (t >> 5) + 8 * it;
      *reinterpret_cast<float4*>(&Vs[k][c4 * 4]) = vreg[it];
    }
    if (more) {
#pragma unroll
      for (int part = 0; part < 4; ++part)
#pragma unroll
        for (int half = 0; half < 2; ++half) {
          int c4 = (t & 7) + 8 * part;
          int r  = (t >> 3) + 32 * half;
          kreg[part * 2 + half] = *reinterpret_cast<const float4*>(
              Kg + (size_t)((kt + 1) * 64 + r) * QKV_N + c4 * 4);
        }
    }
    __syncthreads();

#pragma unroll 16
    for (int k = 0; k < 64; ++k) {
      const int src = (lane & ~15) | (k >> 2);
      float pk[4], vv[8];
#pragma unroll
      for (int i = 0; i < 4; ++i) pk[i] = __shfl(p[i][k & 3], src, 64);
      *reinterpret_cast<float4*>(vv)     = *reinterpret_cast<const float4*>(&Vs[k][tc * 8]);
      *reinterpret_cast<float4*>(vv + 4) = *reinterpret_cast<const float4*>(&Vs[k][tc * 8 + 4]);
#pragma unroll
      for (int i = 0; i < 4; ++i)
#pragma unroll
        for (int jj = 0; jj < 8; ++jj) o[i][jj] = fmaf(pk[i], vv[jj], o[i][jj]);
    }

    __syncthreads();
    if (more) {
#pragma unroll
      for (int part = 0; part < 4; ++part)
#pragma unroll
        for (int half = 0; half < 2; ++half) {
          int c4 = (t & 7) + 8 * part;
          int r  = (t >> 3) + 32 * half;
          float4 v = kreg[part * 2 + half];
          Kt[c4 * 4 + 0][r] = v.x; Kt[c4 * 4 + 1][r] = v.y;
          Kt[c4 * 4 + 2][r] = v.z; Kt[c4 * 4 + 3][r] = v.w;
        }
      __syncthreads();
    }
  }

#pragma unroll
  for (int i = 0; i < 4; ++i) {
    float inv = 1.0f / l_i[i];
    int r = qt * 64 + tr * 4 + i;
    size_t base = ((size_t)(b * S_) + r) * (NH_ * HD_) + h * HD_ + tc * 8;
    if (split) {
      u16 hv[8], lv[8];
#pragma unroll
      for (int jj = 0; jj < 8; ++jj) {
        float v = o[i][jj] * inv;
        hv[jj] = f2bf(v);
        lv[jj] = f2bf(v - bf2f(hv[jj]));
      }
      *reinterpret_cast<ushort4*>(&attn_hi[base])     = make_ushort4(hv[0], hv[1], hv[2], hv[3]);
      *reinterpret_cast<ushort4*>(&attn_hi[base + 4]) = make_ushort4(hv[4], hv[5], hv[6], hv[7]);
      *reinterpret_cast<ushort4*>(&attn_lo[base])     = make_ushort4(lv[0], lv[1], lv[2], lv[3]);
      *reinterpret_cast<ushort4*>(&attn_lo[base + 4]) = make_ushort4(lv[4], lv[5], lv[6], lv[7]);
    } else {
      float4 w0, w1;
      w0.x = o[i][0] * inv; w0.y = o[i][1] * inv;
      w0.z = o[i][2] * inv; w0.w = o[i][3] * inv;
      w1.x = o[i][4] * inv; w1.y = o[i][5] * inv;
      w1.z = o[i][6] * inv; w1.w = o[i][7] * inv;
      *reinterpret_cast<float4*>(&attn_f32[base])     = w0;
      *reinterpret_cast<float4*>(&attn_f32[base + 4]) = w1;
    }
  }
}

// ---------------------------------------------------------------------------
extern "C" void kernel_launch(void* const* d_in, const int* in_sizes, int n_in,
                              void* d_out, int out_size, void* d_ws, size_t ws_size,
                              hipStream_t stream) {
  (void)in_sizes; (void)n_in; (void)out_size;
  const int*   positions = (const int*)d_in[0];
  const float* hidden    = (const float*)d_in[1];
  const float* Wqkv      = (const float*)d_in[2];
  const float* bqkv      = (const float*)d_in[3];
  const float* Wo        = (const float*)d_in[4];
  float* out = (float*)d_out;

  // main-path workspace layout
  char* p = (char*)d_ws;
  float* qkv     = (float*)p;            p += (size_t)M_ * QKV_N * 4;   // 48 MB
  u16*   attn_hi = (u16*)p;              p += (size_t)M_ * H_ * 2;      // 16 MB
  u16*   attn_lo = (u16*)p;              p += (size_t)M_ * H_ * 2;
  u16*   hid_hi  = (u16*)p;              p += (size_t)M_ * H_ * 2;
  u16*   hid_lo  = (u16*)p;              p += (size_t)M_ * H_ * 2;
  u16*   wq_hi   = (u16*)p;              p += (size_t)QKV_N * H_ * 2;   // 12 MB
  u16*   wq_lo   = (u16*)p;              p += (size_t)QKV_N * H_ * 2;
  u16*   wo_hi   = (u16*)p;              p += (size_t)H_ * H_ * 2;      // 8 MB
  u16*   wo_lo   = (u16*)p;              p += (size_t)H_ * H_ * 2;
  const size_t need = (size_t)(p - (char*)d_ws);

  const int rope_total = M_ * (NH_ + NKV_) * (HD_ / 2);

  if (ws_size >= need) {
    // ---- MFMA path ----
    split_f32<<<(M_ * H_ / 4 + 255) / 256, 256, 0, stream>>>(hidden, hid_hi, hid_lo, M_ * H_ / 4);
    split_transpose<<<dim3(H_ / 64, QKV_N / 64), 256, 0, stream>>>(Wqkv, wq_hi, wq_lo, H_, QKV_N);
    split_transpose<<<dim3(H_ / 64, H_ / 64), 256, 0, stream>>>(Wo, wo_hi, wo_lo, H_, H_);

    gemm_bf16x3<<<dim3(M_ / 128, QKV_N / 128), 256, 0, stream>>>(
        hid_hi, hid_lo, wq_hi, wq_lo, bqkv, qkv, M_, QKV_N, H_);

    rope_kernel<<<(rope_total + 255) / 256, 256, 0, stream>>>(qkv, positions);

    flash_attn<<<B_ * NH_ * (S_ / 64), 256, 0, stream>>>(qkv, nullptr, attn_hi, attn_lo, 1);

    gemm_bf16x3<<<dim3(M_ / 128, H_ / 128), 256, 0, stream>>>(
        attn_hi, attn_lo, wo_hi, wo_lo, nullptr, out, M_, H_, H_);
  } else {
    // ---- fp32 fallback (80 MB ws) ----
    float* qkv_f  = (float*)d_ws;
    float* attn_f = qkv_f + (size_t)M_ * QKV_N;
    dim3 g1(M_ / BT, QKV_N / BT);
    sgemm_bias<<<g1, 256, 0, stream>>>(hidden, Wqkv, bqkv, qkv_f, M_, QKV_N, H_);
    rope_kernel<<<(rope_total + 255) / 256, 256, 0, stream>>>(qkv_f, positions);
    flash_attn<<<B_ * NH_ * (S_ / 64), 256, 0, stream>>>(qkv_f, attn_f, nullptr, nullptr, 0);
    dim3 g2(M_ / BT, H_ / BT);
    sgemm_bias<<<g2, 256, 0, stream>>>(attn_f, Wo, nullptr, out, M_, H_, H_);
  }
}

// Round 6
// 512.158 us; speedup vs baseline: 3.9010x; 3.9010x over previous
//
#include <hip/hip_runtime.h>
#include <hip/hip_bf16.h>
#include <cstddef>
#include <cstdint>
#include <math.h>

// Problem constants (Qwen2MoE attention, B=2, S=2048)
#define H_    2048
#define NH_   16
#define NKV_  4
#define HD_   128
#define S_    2048
#define B_    2
#define M_    (B_ * S_)        // 4096 rows
#define QKV_N 3072             // (NH + 2*NKV) * HD

typedef unsigned short u16;
typedef unsigned int   u32;
typedef __attribute__((ext_vector_type(8))) short s16x8;   // 8 bf16 (4 VGPRs)
typedef __attribute__((ext_vector_type(4))) float f32x4;   // MFMA C/D

__device__ inline u16 f2bf(float x) {
  __hip_bfloat16 h = __float2bfloat16(x);
  return *reinterpret_cast<u16*>(&h);
}
__device__ inline float bf2f(u16 u) {
  __hip_bfloat16 h;
  *reinterpret_cast<u16*>(&h) = u;
  return __bfloat162float(h);
}
__device__ inline u32 pack_bf2(float a, float b) {
  return (u32)f2bf(a) | ((u32)f2bf(b) << 16);
}

__device__ inline f32x4 mfma_bf16(s16x8 a, s16x8 b, f32x4 c) {
  return __builtin_amdgcn_mfma_f32_16x16x32_bf16(a, b, c, 0, 0, 0);
}

#define GLOAD(g, s)                                                  \
  __builtin_amdgcn_global_load_lds(                                  \
      (const __attribute__((address_space(1))) void*)(g),            \
      (__attribute__((address_space(3))) void*)(s), 16, 0, 0)

// ---------------------------------------------------------------------------
// split fp32 -> (hi, lo) bf16, elementwise (A matrices, [M][K] layout)
// ---------------------------------------------------------------------------
__global__ __launch_bounds__(256) void split_f32(
    const float* __restrict__ in, u16* __restrict__ hi, u16* __restrict__ lo,
    int n4) {
  int i = blockIdx.x * 256 + threadIdx.x;
  if (i >= n4) return;
  float4 v = reinterpret_cast<const float4*>(in)[i];
  float x[4] = {v.x, v.y, v.z, v.w};
  u16 hv[4], lv[4];
#pragma unroll
  for (int j = 0; j < 4; ++j) {
    hv[j] = f2bf(x[j]);
    lv[j] = f2bf(x[j] - bf2f(hv[j]));
  }
  reinterpret_cast<ushort4*>(hi)[i] = make_ushort4(hv[0], hv[1], hv[2], hv[3]);
  reinterpret_cast<ushort4*>(lo)[i] = make_ushort4(lv[0], lv[1], lv[2], lv[3]);
}

// ---------------------------------------------------------------------------
// split + transpose: W[K][N] fp32 -> Wt_hi/lo[N][K] bf16 (64x64 LDS tile)
// ---------------------------------------------------------------------------
__global__ __launch_bounds__(256) void split_transpose(
    const float* __restrict__ W, u16* __restrict__ thi, u16* __restrict__ tlo,
    int K, int N) {
  __shared__ float tile[64][65];
  const int t  = threadIdx.x;
  const int rr = t >> 4;
  const int c4 = (t & 15) * 4;
  const int k0 = blockIdx.x * 64;
  const int n0 = blockIdx.y * 64;
#pragma unroll
  for (int s = 0; s < 4; ++s) {
    int kk = rr + 16 * s;
    float4 v = *reinterpret_cast<const float4*>(&W[(size_t)(k0 + kk) * N + n0 + c4]);
    tile[kk][c4 + 0] = v.x; tile[kk][c4 + 1] = v.y;
    tile[kk][c4 + 2] = v.z; tile[kk][c4 + 3] = v.w;
  }
  __syncthreads();
#pragma unroll
  for (int s = 0; s < 4; ++s) {
    int nn = rr + 16 * s;
    u16 hv[4], lv[4];
#pragma unroll
    for (int j = 0; j < 4; ++j) {
      float x = tile[c4 + j][nn];
      hv[j] = f2bf(x);
      lv[j] = f2bf(x - bf2f(hv[j]));
    }
    size_t o = (size_t)(n0 + nn) * K + k0 + c4;
    *reinterpret_cast<ushort4*>(&thi[o]) = make_ushort4(hv[0], hv[1], hv[2], hv[3]);
    *reinterpret_cast<ushort4*>(&tlo[o]) = make_ushort4(lv[0], lv[1], lv[2], lv[3]);
  }
}

// ---------------------------------------------------------------------------
// bf16x3 split MFMA GEMM (validated r4).
// ---------------------------------------------------------------------------
__global__ __launch_bounds__(256, 2) void gemm_bf16x3(
    const u16* __restrict__ Ahi, const u16* __restrict__ Alo,
    const u16* __restrict__ Bthi, const u16* __restrict__ Btlo,
    const float* __restrict__ bias, float* __restrict__ C,
    int M, int N, int K) {
  __shared__ u16 lds[4][128][32];

  const int t  = threadIdx.x;
  const int l  = t & 63;
  const int w  = t >> 6;
  const int wr = w >> 1, wc = w & 1;
  const int row0 = blockIdx.x * 128;
  const int col0 = blockIdx.y * 128;

  f32x4 acc[4][4] = {};

  const int srow  = l >> 2;
  const int gslot = (l & 3) ^ ((l >> 3) & 3);
  const int fr    = l & 15;
  const int rslot = (l >> 4) ^ ((fr >> 1) & 3);

  for (int k0 = 0; k0 < K; k0 += 32) {
#pragma unroll
    for (int it = 0; it < 2; ++it) {
      const int r0 = (w + 4 * it) * 16;
      const size_t ga = (size_t)(row0 + r0 + srow) * K + k0 + gslot * 8;
      GLOAD(Ahi + ga, &lds[0][r0][0]);
      GLOAD(Alo + ga, &lds[1][r0][0]);
      const size_t gb = (size_t)(col0 + r0 + srow) * K + k0 + gslot * 8;
      GLOAD(Bthi + gb, &lds[2][r0][0]);
      GLOAD(Btlo + gb, &lds[3][r0][0]);
    }
    __syncthreads();

    s16x8 ah[4], al[4];
#pragma unroll
    for (int f = 0; f < 4; ++f) {
      const int ar = wr * 64 + f * 16 + fr;
      ah[f] = *reinterpret_cast<const s16x8*>(&lds[0][ar][rslot * 8]);
      al[f] = *reinterpret_cast<const s16x8*>(&lds[1][ar][rslot * 8]);
    }
#pragma unroll
    for (int j = 0; j < 4; ++j) {
      const int br = wc * 64 + j * 16 + fr;
      const s16x8 bh = *reinterpret_cast<const s16x8*>(&lds[2][br][rslot * 8]);
      const s16x8 bl = *reinterpret_cast<const s16x8*>(&lds[3][br][rslot * 8]);
#pragma unroll
      for (int i = 0; i < 4; ++i) {
        acc[i][j] = mfma_bf16(ah[i], bh, acc[i][j]);
        acc[i][j] = mfma_bf16(al[i], bh, acc[i][j]);
        acc[i][j] = mfma_bf16(ah[i], bl, acc[i][j]);
      }
    }
    __syncthreads();
  }

  const int rb = (l >> 4) * 4;
  const int cn = l & 15;
  float bv[4];
#pragma unroll
  for (int j = 0; j < 4; ++j)
    bv[j] = bias ? bias[col0 + wc * 64 + j * 16 + cn] : 0.f;
#pragma unroll
  for (int i = 0; i < 4; ++i)
#pragma unroll
    for (int j = 0; j < 4; ++j) {
      const int col = col0 + wc * 64 + j * 16 + cn;
#pragma unroll
      for (int r = 0; r < 4; ++r) {
        const int row = row0 + wr * 64 + i * 16 + rb + r;
        C[(size_t)row * N + col] = acc[i][j][r] + bv[j];
      }
    }
}

// ---------------------------------------------------------------------------
// prep_qk: RoPE (fp32 math) + cast to bf16.
// Writes q_bf[b][h][s][128] and k_bf[b][kvh][s][128].
// ---------------------------------------------------------------------------
__global__ __launch_bounds__(256) void prep_qk(
    const float* __restrict__ qkv, const int* __restrict__ positions,
    u16* __restrict__ q_bf, u16* __restrict__ k_bf) {
  int idx = blockIdx.x * 256 + threadIdx.x;
  const int total = M_ * (NH_ + NKV_) * 64;
  if (idx >= total) return;
  int j    = idx & 63;
  int head = (idx >> 6) % (NH_ + NKV_);
  int m    = idx / (64 * (NH_ + NKV_));
  int b    = m >> 11;
  int s    = m & 2047;
  float pos = (float)positions[m];
  float inv_freq = powf(1.0e6f, -(float)j * (1.0f / 64.0f));
  float ang = pos * inv_freq;
  float sn, cs;
  sincosf(ang, &sn, &cs);
  const float* src = qkv + (size_t)m * QKV_N + head * HD_ + j;
  float x1 = src[0], x2 = src[64];
  float y1 = x1 * cs - x2 * sn;
  float y2 = x2 * cs + x1 * sn;
  u16* dst;
  if (head < NH_) {
    dst = q_bf + (((size_t)(b * NH_ + head)) * S_ + s) * HD_ + j;
  } else {
    dst = k_bf + (((size_t)(b * NKV_ + (head - NH_))) * S_ + s) * HD_ + j;
  }
  dst[0]  = f2bf(y1);
  dst[64] = f2bf(y2);
}

// ---------------------------------------------------------------------------
// prep_v: V slice of qkv -> transposed bf16 vT[b][kvh][d=128][s=2048].
// ---------------------------------------------------------------------------
__global__ __launch_bounds__(256) void prep_v(
    const float* __restrict__ qkv, u16* __restrict__ vT) {
  __shared__ float tile[64][65];
  const int bk = blockIdx.x;           // b*NKV + kvh
  const int s0 = blockIdx.y * 64;
  const int d0 = blockIdx.z * 64;
  const int t  = threadIdx.x;
  const float* src = qkv + ((size_t)(bk >> 2) * S_) * QKV_N
                     + (NH_ + NKV_) * HD_ + (bk & 3) * HD_ + d0;
  {
    const int r  = t >> 2;
    const int c0 = (t & 3) * 16;
    const float* row = src + (size_t)(s0 + r) * QKV_N;
#pragma unroll
    for (int i = 0; i < 4; ++i) {
      float4 v = *reinterpret_cast<const float4*>(row + c0 + i * 4);
      tile[r][c0 + i*4 + 0] = v.x; tile[r][c0 + i*4 + 1] = v.y;
      tile[r][c0 + i*4 + 2] = v.z; tile[r][c0 + i*4 + 3] = v.w;
    }
  }
  __syncthreads();
  {
    const int d  = t >> 2;
    const int sc = (t & 3) * 16;
    u16 buf[16];
#pragma unroll
    for (int i = 0; i < 16; ++i) buf[i] = f2bf(tile[sc + i][d]);
    u16* dst = vT + ((size_t)bk * HD_ + d0 + d) * S_ + s0 + sc;
    *reinterpret_cast<ushort4*>(dst + 0)  = *reinterpret_cast<ushort4*>(&buf[0]);
    *reinterpret_cast<ushort4*>(dst + 4)  = *reinterpret_cast<ushort4*>(&buf[4]);
    *reinterpret_cast<ushort4*>(dst + 8)  = *reinterpret_cast<ushort4*>(&buf[8]);
    *reinterpret_cast<ushort4*>(dst + 12) = *reinterpret_cast<ushort4*>(&buf[12]);
  }
}

// ---------------------------------------------------------------------------
// MFMA flash attention (bf16 QK^T and PV, fp32 online softmax, causal, GQA).
// Block = (b, h, 64 q-rows); 4 waves x 16 q-rows. Swapped QK^T:
// S^T = mfma(A=K, B=Q) -> lane holds 16 kv-scores of q-row (lane&15).
// K [64][128] / V^T [128][64] staged via global_load_lds with both-sides
// XOR slot swizzle (slot ^ (row&7)); P via per-wave LDS (b32 write / b128
// read, XOR (q&7)<<2 on u32 index).
// Epilogue writes split hi/lo bf16 for gemm_bf16x3.
// ---------------------------------------------------------------------------
__global__ __launch_bounds__(256, 2) void flash_mfma(
    const u16* __restrict__ q_bf, const u16* __restrict__ k_bf,
    const u16* __restrict__ vT_bf,
    u16* __restrict__ attn_hi, u16* __restrict__ attn_lo) {
  __shared__ u16 Kl[64 * 128];        // 16 KB
  __shared__ u16 Vl[128 * 64];        // 16 KB (V transposed: [d][kv])
  __shared__ u16 Pl[4 * 16 * 64];     // 8 KB  (per-wave P[16 q][64 kv])

  const int t   = threadIdx.x;
  const int l   = t & 63;
  const int w   = t >> 6;
  const int bid = blockIdx.x;
  const int qt  = 31 - (bid & 31);    // heavy q-tiles dispatch first
  const int bh  = bid >> 5;
  const int h   = bh & 15;
  const int b   = bh >> 4;
  const int kvh = h >> 2;

  const int ln = l & 15;              // q-col / frag row / d-col
  const int lh = l >> 4;              // k-slot group

  const int q0 = qt * 64 + w * 16;    // this wave's global q base
  const u16* Qg = q_bf  + (((size_t)(b * NH_ + h)) * S_ + q0) * HD_;
  const u16* Kg = k_bf  + ((size_t)(b * NKV_ + kvh)) * S_ * HD_;
  const u16* Vg = vT_bf + ((size_t)(b * NKV_ + kvh)) * HD_ * S_;

  // Q fragments in registers (A/B frag layout: row ln, k-elems lh*8..)
  s16x8 qf[4];
#pragma unroll
  for (int c = 0; c < 4; ++c)
    qf[c] = *reinterpret_cast<const s16x8*>(Qg + (size_t)ln * HD_ + c * 32 + lh * 8);

  f32x4 o[8] = {};                    // O[q-rows lh*4+reg][d-tile dt*16+ln]
  float mrow = -INFINITY, lrow = 0.f; // state for q-row (q0 + ln), replicated x4

  const float scale = 0.08838834764831845f;  // 128^-0.5
  const int nkt = qt + 1;
  u32* const Pw = reinterpret_cast<u32*>(&Pl[0]) + w * 512 + ln * 32;
  const u32 qm = (u32)((ln & 7) << 2);

  for (int kt = 0; kt < nkt; ++kt) {
    const int kv0 = kt * 64;
    __syncthreads();  // prior tile's K/V reads complete before restage

    // stage K tile [64][128]: per wave-issue 1 KB = 4 rows
#pragma unroll
    for (int i = 0; i < 4; ++i) {
      const int seg = w + 4 * i;              // 0..15
      const int r   = seg * 4 + lh;           // kv-local row this lane fetches
      const int s   = ln;                     // 16B slot 0..15
      GLOAD(Kg + (size_t)(kv0 + r) * HD_ + ((s ^ (r & 7)) * 8), Kl + seg * 512);
    }
    // stage V^T tile [128][64]: per wave-issue 1 KB = 8 rows
#pragma unroll
    for (int i = 0; i < 4; ++i) {
      const int seg = w + 4 * i;
      const int d   = seg * 8 + (l >> 3);     // d row this lane fetches
      const int s   = l & 7;                  // 16B slot 0..7
      GLOAD(Vg + (size_t)d * S_ + kv0 + ((s ^ (d & 7)) * 8), Vl + seg * 512);
    }
    __syncthreads();  // vmcnt(0) drained by compiler before barrier

    // ---- S^T[kv][q] = K · Q^T : 16 MFMAs ----
    f32x4 sa[4] = {};
#pragma unroll
    for (int a = 0; a < 4; ++a) {
      const int row = a * 16 + ln;            // kv-local
#pragma unroll
      for (int c = 0; c < 4; ++c) {
        const int slot = (c * 4 + lh) ^ (row & 7);
        const s16x8 kf = *reinterpret_cast<const s16x8*>(&Kl[row * 128 + slot * 8]);
        sa[a] = mfma_bf16(kf, qf[c], sa[a]);
      }
    }

    // ---- scale + causal mask + online softmax (per q-row = ln) ----
    float p[16];
    float lm = -INFINITY;
#pragma unroll
    for (int a = 0; a < 4; ++a)
#pragma unroll
      for (int r = 0; r < 4; ++r) {
        float sv = sa[a][r] * scale;
        const int kvg = kv0 + a * 16 + lh * 4 + r;
        if (kt == qt && kvg > q0 + ln) sv = -INFINITY;
        p[a * 4 + r] = sv;
        lm = fmaxf(lm, sv);
      }
    lm = fmaxf(lm, __shfl_xor(lm, 16, 64));
    lm = fmaxf(lm, __shfl_xor(lm, 32, 64));
    const float mnew  = fmaxf(mrow, lm);
    const float alpha = __expf(mrow - mnew);
    mrow = mnew;
    float rs = 0.f;
#pragma unroll
    for (int i = 0; i < 16; ++i) {
      p[i] = __expf(p[i] - mnew);
      rs += p[i];
    }
    rs += __shfl_xor(rs, 16, 64);
    rs += __shfl_xor(rs, 32, 64);
    lrow = lrow * alpha + rs;

    // ---- write P (bf16) to per-wave LDS, swizzled ----
#pragma unroll
    for (int a = 0; a < 4; ++a) {
      const u32 u0 = (u32)(a * 8 + lh * 2);   // kv/2 for r=0,1
      Pw[u0 ^ qm]       = pack_bf2(p[a * 4 + 0], p[a * 4 + 1]);
      Pw[(u0 + 1) ^ qm] = pack_bf2(p[a * 4 + 2], p[a * 4 + 3]);
    }

    // ---- rescale O by alpha of each O-row (broadcast from softmax lanes) ----
    float af[4];
#pragma unroll
    for (int r = 0; r < 4; ++r)
      af[r] = __shfl(alpha, (l & 48) | (lh * 4 + r), 64);
#pragma unroll
    for (int dt = 0; dt < 8; ++dt)
#pragma unroll
      for (int r = 0; r < 4; ++r) o[dt][r] *= af[r];

    __threadfence_block();  // order P writes before P reads (cross-lane)

    // ---- PV: O[16 q][128 d] += P[16][64] · V[64][128] : 16 MFMAs ----
#pragma unroll
    for (int kc = 0; kc < 2; ++kc) {
      const u32 ub = ((u32)(kc * 16 + lh * 4)) ^ qm;
      const s16x8 pf = *reinterpret_cast<const s16x8*>(Pw + ub);
#pragma unroll
      for (int dt = 0; dt < 8; ++dt) {
        const int d    = dt * 16 + ln;
        const int slot = (kc * 4 + lh) ^ (d & 7);
        const s16x8 vf = *reinterpret_cast<const s16x8*>(&Vl[d * 64 + slot * 8]);
        o[dt] = mfma_bf16(pf, vf, o[dt]);
      }
    }
  }

  // ---- epilogue: O/l, write split hi/lo bf16 attn[b, q, h*128 + d] ----
  float li[4];
#pragma unroll
  for (int r = 0; r < 4; ++r)
    li[r] = 1.f / __shfl(lrow, (l & 48) | (lh * 4 + r), 64);
#pragma unroll
  for (int r = 0; r < 4; ++r) {
    const size_t rowg = (size_t)(b * S_) + q0 + lh * 4 + r;
    u16* oh = attn_hi + rowg * (NH_ * HD_) + h * HD_;
    u16* ol = attn_lo + rowg * (NH_ * HD_) + h * HD_;
#pragma unroll
    for (int dt = 0; dt < 8; ++dt) {
      const float v = o[dt][r] * li[r];
      const u16 hv = f2bf(v);
      oh[dt * 16 + ln] = hv;
      ol[dt * 16 + ln] = f2bf(v - bf2f(hv));
    }
  }
}

// ---------------------------------------------------------------------------
extern "C" void kernel_launch(void* const* d_in, const int* in_sizes, int n_in,
                              void* d_out, int out_size, void* d_ws, size_t ws_size,
                              hipStream_t stream) {
  (void)in_sizes; (void)n_in; (void)out_size; (void)ws_size;
  const int*   positions = (const int*)d_in[0];
  const float* hidden    = (const float*)d_in[1];
  const float* Wqkv      = (const float*)d_in[2];
  const float* bqkv      = (const float*)d_in[3];
  const float* Wo        = (const float*)d_in[4];
  float* out = (float*)d_out;

  // workspace layout (152 MB total — same budget as validated r4 run).
  char* p = (char*)d_ws;
  float* qkv     = (float*)p;  p += (size_t)M_ * QKV_N * 4;   // 48 MB
  u16*   attn_hi = (u16*)p;    p += (size_t)M_ * H_ * 2;      // 16 MB
  u16*   attn_lo = (u16*)p;    p += (size_t)M_ * H_ * 2;      // 16 MB
  u16*   hid_hi  = (u16*)p;    p += (size_t)M_ * H_ * 2;      // 16 MB
  u16*   hid_lo  = (u16*)p;    p += (size_t)M_ * H_ * 2;      // 16 MB
  u16*   wq_hi   = (u16*)p;    p += (size_t)QKV_N * H_ * 2;   // 12 MB
  u16*   wq_lo   = (u16*)p;    p += (size_t)QKV_N * H_ * 2;   // 12 MB
  u16*   wo_hi   = (u16*)p;    p += (size_t)H_ * H_ * 2;      // 8 MB
  u16*   wo_lo   = (u16*)p;    p += (size_t)H_ * H_ * 2;      // 8 MB

  // overlays (dead-after-gemm1 regions)
  u16* q_bf = hid_hi;                                   // 16 MB
  u16* k_bf = hid_lo;                                   // 4 MB
  u16* vT   = hid_lo + (size_t)B_ * NKV_ * S_ * HD_;    // 4 MB

  split_f32<<<(M_ * H_ / 4 + 255) / 256, 256, 0, stream>>>(
      hidden, hid_hi, hid_lo, M_ * H_ / 4);
  split_transpose<<<dim3(H_ / 64, QKV_N / 64), 256, 0, stream>>>(
      Wqkv, wq_hi, wq_lo, H_, QKV_N);
  split_transpose<<<dim3(H_ / 64, H_ / 64), 256, 0, stream>>>(
      Wo, wo_hi, wo_lo, H_, H_);

  gemm_bf16x3<<<dim3(M_ / 128, QKV_N / 128), 256, 0, stream>>>(
      hid_hi, hid_lo, wq_hi, wq_lo, bqkv, qkv, M_, QKV_N, H_);

  const int qk_total = M_ * (NH_ + NKV_) * 64;
  prep_qk<<<(qk_total + 255) / 256, 256, 0, stream>>>(qkv, positions, q_bf, k_bf);
  prep_v<<<dim3(B_ * NKV_, S_ / 64, HD_ / 64), 256, 0, stream>>>(qkv, vT);

  flash_mfma<<<B_ * NH_ * (S_ / 64), 256, 0, stream>>>(
      q_bf, k_bf, vT, attn_hi, attn_lo);

  gemm_bf16x3<<<dim3(M_ / 128, H_ / 128), 256, 0, stream>>>(
      attn_hi, attn_lo, wo_hi, wo_lo, nullptr, out, M_, H_, H_);
}